// Round 6
// baseline (751.430 us; speedup 1.0000x reference)
//
#include <hip/hip_runtime.h>

#define NH 128
#define LAYERS 4

__device__ __forceinline__ unsigned short f2bf(float f) {
    unsigned u = __float_as_uint(f);
    u += 0x7fffu + ((u >> 16) & 1u);          // round-to-nearest-even
    return (unsigned short)(u >> 16);
}

// ---------------- fused: edge-dst histogram + gstart boundary detection --------------
__global__ void hist_gstart_kernel(const int* __restrict__ dst, int* __restrict__ deg, int E,
                                   const int* __restrict__ batch, int* __restrict__ gstart,
                                   int N, int G) {
    int i = blockIdx.x * blockDim.x + threadIdx.x;
    if (i < E) atomicAdd(&deg[dst[i]], 1);
    if (i < N) {
        int b = batch[i];
        int prev = (i == 0) ? -1 : batch[i - 1];
        for (int g = prev + 1; g <= b; ++g) gstart[g] = i;
        if (i == N - 1)
            for (int g = b + 1; g <= G; ++g) gstart[g] = N;
    }
}

// ---------------- hierarchical scan ----------------
__global__ __launch_bounds__(256) void block_sum_kernel(const int* __restrict__ deg,
                                                        int* __restrict__ bsum, int n) {
    __shared__ int red[256];
    int t = threadIdx.x;
    int base = blockIdx.x * 1024;
    int s = 0;
#pragma unroll
    for (int i = 0; i < 4; ++i) {
        int idx = base + i * 256 + t;
        if (idx < n) s += deg[idx];
    }
    red[t] = s;
    __syncthreads();
    for (int off = 128; off > 0; off >>= 1) {
        if (t < off) red[t] += red[t + off];
        __syncthreads();
    }
    if (t == 0) bsum[blockIdx.x] = red[0];
}

__global__ __launch_bounds__(1024) void scan_partials_kernel(int* __restrict__ bsum, int nb,
                                                             int* __restrict__ row_start, int n) {
    __shared__ int part[1024];
    int t = threadIdx.x;
    int v = (t < nb) ? bsum[t] : 0;
    part[t] = v;
    __syncthreads();
    for (int off = 1; off < 1024; off <<= 1) {
        int u = (t >= off) ? part[t - off] : 0;
        __syncthreads();
        part[t] += u;
        __syncthreads();
    }
    if (t < nb) bsum[t] = part[t] - v;
    if (t == 1023) row_start[n] = part[1023];
}

__global__ __launch_bounds__(256) void local_scan_kernel(const int* __restrict__ deg,
                                                         const int* __restrict__ bsum,
                                                         int* __restrict__ row_start,
                                                         int* __restrict__ cursor, int n) {
    __shared__ int part[256];
    int t = threadIdx.x;
    int base = blockIdx.x * 1024 + t * 4;
    int v0 = 0, v1 = 0, v2 = 0, v3 = 0;
    if (base + 3 < n) {
        int4 v = *(const int4*)(deg + base);
        v0 = v.x; v1 = v.y; v2 = v.z; v3 = v.w;
    } else {
        if (base + 0 < n) v0 = deg[base + 0];
        if (base + 1 < n) v1 = deg[base + 1];
        if (base + 2 < n) v2 = deg[base + 2];
        if (base + 3 < n) v3 = deg[base + 3];
    }
    int tsum = v0 + v1 + v2 + v3;
    part[t] = tsum;
    __syncthreads();
    for (int off = 1; off < 256; off <<= 1) {
        int u = (t >= off) ? part[t - off] : 0;
        __syncthreads();
        part[t] += u;
        __syncthreads();
    }
    int run = bsum[blockIdx.x] + part[t] - tsum;
    int r0 = run, r1 = run + v0, r2 = r1 + v1, r3 = r2 + v2;
    if (base + 3 < n) {
        *(int4*)(row_start + base) = make_int4(r0, r1, r2, r3);
        *(int4*)(cursor + base) = make_int4(r0, r1, r2, r3);
    } else {
        if (base + 0 < n) { row_start[base + 0] = r0; cursor[base + 0] = r0; }
        if (base + 1 < n) { row_start[base + 1] = r1; cursor[base + 1] = r1; }
        if (base + 2 < n) { row_start[base + 2] = r2; cursor[base + 2] = r2; }
        if (base + 3 < n) { row_start[base + 3] = r3; cursor[base + 3] = r3; }
    }
}

// ---------------- scatter: single int2 {src, eid} payload per edge -------------------
__global__ void scatter_kernel(const int* __restrict__ src, const int* __restrict__ dst,
                               int* __restrict__ cursor, int2* __restrict__ pk, int E) {
    int e = blockIdx.x * blockDim.x + threadIdx.x;
    if (e < E) {
        int d = dst[e];
        int p = atomicAdd(&cursor[d], 1);
        pk[p] = make_int2(src[e], e);
    }
}

// ---------------- easum ----------------
__global__ __launch_bounds__(256) void easum_kernel(const float* __restrict__ edge_attr,
                                                    const int2* __restrict__ pk,
                                                    const int* __restrict__ row_start,
                                                    float* __restrict__ easum, int N) {
    int t = threadIdx.x;
    int node = blockIdx.x * 16 + (t >> 4);
    int k = t & 15;
    if (node >= N) return;
    int rs = row_start[node], re = row_start[node + 1];
    float acc = 0.f;
    for (int p = rs; p < re; ++p)
        acc += edge_attr[(size_t)pk[p].y * 16 + k];
    easum[node * 16 + k] = acc;
}

// ---------------- aggregate: x = h + sum_in bf16(h[src]) + easum@We + deg*be ---------
__global__ __launch_bounds__(256) void aggregate_kernel(
    const float* __restrict__ h, const unsigned* __restrict__ hbfu,
    const int2* __restrict__ pk, const int* __restrict__ row_start,
    const float* __restrict__ easum,
    const float* __restrict__ We, const float* __restrict__ be,
    float* __restrict__ x, int N) {
    __shared__ float2 WeL[16 * 64];
    int t = threadIdx.x;
    const float2* Wg2 = (const float2*)We;
    for (int i = t; i < 16 * 64; i += 256) WeL[i] = Wg2[i];
    __syncthreads();

    int wave = t >> 6, lane = t & 63;
    int n = blockIdx.x * 4 + wave;
    if (n >= N) return;
    const float2* h2 = (const float2*)h;
    float2 acc = h2[(size_t)n * 64 + lane];    // self term, fp32
    float2 acc2 = make_float2(0.f, 0.f);
    float2 acc3 = make_float2(0.f, 0.f);
    float2 acc4 = make_float2(0.f, 0.f);
    int rs = row_start[n], re = row_start[n + 1];
    float myea = (lane < 16) ? easum[n * 16 + lane] : 0.f;

    for (int base = rs; base < re; base += 64) {
        int cnt = min(64, re - base);
        int myS = (base + lane < re) ? pk[base + lane].x : 0;
        int j = 0;
        for (; j + 15 < cnt; j += 16) {
            int s0 = __shfl(myS, j);      int s1 = __shfl(myS, j + 1);
            int s2 = __shfl(myS, j + 2);  int s3 = __shfl(myS, j + 3);
            int s4 = __shfl(myS, j + 4);  int s5 = __shfl(myS, j + 5);
            int s6 = __shfl(myS, j + 6);  int s7 = __shfl(myS, j + 7);
            int s8 = __shfl(myS, j + 8);  int s9 = __shfl(myS, j + 9);
            int sa = __shfl(myS, j + 10); int sb = __shfl(myS, j + 11);
            int sc = __shfl(myS, j + 12); int sd = __shfl(myS, j + 13);
            int se = __shfl(myS, j + 14); int sf = __shfl(myS, j + 15);
            unsigned u0 = hbfu[(size_t)s0 * 64 + lane];
            unsigned u1 = hbfu[(size_t)s1 * 64 + lane];
            unsigned u2 = hbfu[(size_t)s2 * 64 + lane];
            unsigned u3 = hbfu[(size_t)s3 * 64 + lane];
            unsigned u4 = hbfu[(size_t)s4 * 64 + lane];
            unsigned u5 = hbfu[(size_t)s5 * 64 + lane];
            unsigned u6 = hbfu[(size_t)s6 * 64 + lane];
            unsigned u7 = hbfu[(size_t)s7 * 64 + lane];
            unsigned u8 = hbfu[(size_t)s8 * 64 + lane];
            unsigned u9 = hbfu[(size_t)s9 * 64 + lane];
            unsigned ua = hbfu[(size_t)sa * 64 + lane];
            unsigned ub = hbfu[(size_t)sb * 64 + lane];
            unsigned uc = hbfu[(size_t)sc * 64 + lane];
            unsigned ud = hbfu[(size_t)sd * 64 + lane];
            unsigned ue = hbfu[(size_t)se * 64 + lane];
            unsigned uf = hbfu[(size_t)sf * 64 + lane];
            acc.x  += __uint_as_float(u0 << 16) + __uint_as_float(u1 << 16)
                    + __uint_as_float(u2 << 16) + __uint_as_float(u3 << 16);
            acc.y  += __uint_as_float(u0 & 0xffff0000u) + __uint_as_float(u1 & 0xffff0000u)
                    + __uint_as_float(u2 & 0xffff0000u) + __uint_as_float(u3 & 0xffff0000u);
            acc2.x += __uint_as_float(u4 << 16) + __uint_as_float(u5 << 16)
                    + __uint_as_float(u6 << 16) + __uint_as_float(u7 << 16);
            acc2.y += __uint_as_float(u4 & 0xffff0000u) + __uint_as_float(u5 & 0xffff0000u)
                    + __uint_as_float(u6 & 0xffff0000u) + __uint_as_float(u7 & 0xffff0000u);
            acc3.x += __uint_as_float(u8 << 16) + __uint_as_float(u9 << 16)
                    + __uint_as_float(ua << 16) + __uint_as_float(ub << 16);
            acc3.y += __uint_as_float(u8 & 0xffff0000u) + __uint_as_float(u9 & 0xffff0000u)
                    + __uint_as_float(ua & 0xffff0000u) + __uint_as_float(ub & 0xffff0000u);
            acc4.x += __uint_as_float(uc << 16) + __uint_as_float(ud << 16)
                    + __uint_as_float(ue << 16) + __uint_as_float(uf << 16);
            acc4.y += __uint_as_float(uc & 0xffff0000u) + __uint_as_float(ud & 0xffff0000u)
                    + __uint_as_float(ue & 0xffff0000u) + __uint_as_float(uf & 0xffff0000u);
        }
        for (; j + 3 < cnt; j += 4) {
            int s0 = __shfl(myS, j);
            int s1 = __shfl(myS, j + 1);
            int s2 = __shfl(myS, j + 2);
            int s3 = __shfl(myS, j + 3);
            unsigned u0 = hbfu[(size_t)s0 * 64 + lane];
            unsigned u1 = hbfu[(size_t)s1 * 64 + lane];
            unsigned u2 = hbfu[(size_t)s2 * 64 + lane];
            unsigned u3 = hbfu[(size_t)s3 * 64 + lane];
            acc.x += __uint_as_float(u0 << 16) + __uint_as_float(u1 << 16)
                   + __uint_as_float(u2 << 16) + __uint_as_float(u3 << 16);
            acc.y += __uint_as_float(u0 & 0xffff0000u) + __uint_as_float(u1 & 0xffff0000u)
                   + __uint_as_float(u2 & 0xffff0000u) + __uint_as_float(u3 & 0xffff0000u);
        }
        for (; j < cnt; ++j) {
            int s = __shfl(myS, j);
            unsigned u = hbfu[(size_t)s * 64 + lane];
            acc.x += __uint_as_float(u << 16);
            acc.y += __uint_as_float(u & 0xffff0000u);
        }
    }
    acc.x += (acc2.x + acc3.x) + acc4.x;
    acc.y += (acc2.y + acc3.y) + acc4.y;

    float degf = (float)(re - rs);
    float2 be2 = ((const float2*)be)[lane];
#pragma unroll
    for (int k = 0; k < 16; ++k) {
        float e = __shfl(myea, k);
        float2 w = WeL[k * 64 + lane];
        acc.x = fmaf(e, w.x, acc.x);
        acc.y = fmaf(e, w.y, acc.y);
    }
    acc.x += degf * be2.x;
    acc.y += degf * be2.y;
    ((float2*)x)[(size_t)n * 64 + lane] = acc;
}

// ---------------- GEMM: Z = X @ W + b, 128-row tiles ---------------------------------
__global__ __launch_bounds__(256) void gemm128_kernel(
    const float* __restrict__ X, const float* __restrict__ W, const float* __restrict__ b,
    float* __restrict__ Z, int N, float* __restrict__ bnsum, float* __restrict__ bnsumsq,
    unsigned short* __restrict__ hbf) {
    __shared__ float Wl[64 * NH];
    __shared__ float Xl[NH * 64];
    int t = threadIdx.x;
    int row0 = blockIdx.x * 128;
    int tcol = t & 31, trow = t >> 5;

    float4 bias = ((const float4*)b)[tcol];
    float4 acc[16];
#pragma unroll
    for (int r = 0; r < 16; ++r) acc[r] = bias;

    float4* Wl4 = (float4*)Wl;
    float4* Xl4 = (float4*)Xl;
    const float4* Wg4 = (const float4*)W;
    const float4* Xg4 = (const float4*)X;

    for (int half = 0; half < 2; ++half) {
        __syncthreads();
        for (int i = t; i < 64 * 32; i += 256) Wl4[i] = Wg4[half * 64 * 32 + i];
        for (int i = t; i < 128 * 16; i += 256) {
            int r = i >> 4, kq = i & 15;
            int gr = row0 + r;
            Xl4[i] = (gr < N) ? Xg4[(size_t)gr * 32 + half * 16 + kq]
                              : make_float4(0.f, 0.f, 0.f, 0.f);
        }
        __syncthreads();
        for (int k4 = 0; k4 < 16; ++k4) {
            float4 w0 = Wl4[(k4 * 4 + 0) * 32 + tcol];
            float4 w1 = Wl4[(k4 * 4 + 1) * 32 + tcol];
            float4 w2 = Wl4[(k4 * 4 + 2) * 32 + tcol];
            float4 w3 = Wl4[(k4 * 4 + 3) * 32 + tcol];
#pragma unroll
            for (int r = 0; r < 16; ++r) {
                float4 a = Xl4[(trow * 16 + r) * 16 + k4];
                acc[r].x = fmaf(a.x, w0.x, fmaf(a.y, w1.x, fmaf(a.z, w2.x, fmaf(a.w, w3.x, acc[r].x))));
                acc[r].y = fmaf(a.x, w0.y, fmaf(a.y, w1.y, fmaf(a.z, w2.y, fmaf(a.w, w3.y, acc[r].y))));
                acc[r].z = fmaf(a.x, w0.z, fmaf(a.y, w1.z, fmaf(a.z, w2.z, fmaf(a.w, w3.z, acc[r].z))));
                acc[r].w = fmaf(a.x, w0.w, fmaf(a.y, w1.w, fmaf(a.z, w2.w, fmaf(a.w, w3.w, acc[r].w))));
            }
        }
    }

#pragma unroll
    for (int r = 0; r < 16; ++r) {
        int gr = row0 + trow * 16 + r;
        if (gr < N) {
            ((float4*)Z)[(size_t)gr * 32 + tcol] = acc[r];
            if (hbf)
                ((ushort4*)hbf)[(size_t)gr * 32 + tcol] =
                    make_ushort4(f2bf(acc[r].x), f2bf(acc[r].y), f2bf(acc[r].z), f2bf(acc[r].w));
        }
    }

    if (bnsum) {
        float4 s = make_float4(0.f, 0.f, 0.f, 0.f), q = make_float4(0.f, 0.f, 0.f, 0.f);
#pragma unroll
        for (int r = 0; r < 16; ++r) {
            int gr = row0 + trow * 16 + r;
            if (gr < N) {
                s.x += acc[r].x; s.y += acc[r].y; s.z += acc[r].z; s.w += acc[r].w;
                q.x += acc[r].x * acc[r].x; q.y += acc[r].y * acc[r].y;
                q.z += acc[r].z * acc[r].z; q.w += acc[r].w * acc[r].w;
            }
        }
        __syncthreads();
        ((float4*)Xl)[trow * 32 + tcol] = s;
        ((float4*)Wl)[trow * 32 + tcol] = q;
        __syncthreads();
        if (t < NH) {
            float ss = 0.f, qq = 0.f;
#pragma unroll
            for (int r8 = 0; r8 < 8; ++r8) {
                ss += Xl[r8 * NH + t];
                qq += Wl[r8 * NH + t];
            }
            atomicAdd(&bnsum[t], ss);
            atomicAdd(&bnsumsq[t], qq);
        }
    }
}

// ---------------- fused: BN finalize + h=relu(z*sc+sh)+h + hbf + pool ----------------
__global__ __launch_bounds__(256) void update_pool_kernel(
    const float* __restrict__ z, float* __restrict__ h, unsigned short* __restrict__ hbf,
    const float* __restrict__ bnsum, const float* __restrict__ bnsumsq,
    const float* __restrict__ gamma, const float* __restrict__ beta,
    float invN, const int* __restrict__ gstart, float* __restrict__ pooled) {
    int g = blockIdx.x, t = threadIdx.x;
    __shared__ float scL[NH], shL[NH];
    __shared__ float red[256];
    if (t < NH) {
        float mu = bnsum[t] * invN;
        float var = fmaf(bnsumsq[t], invN, -mu * mu);
        float sc = gamma[t] * rsqrtf(var + 1e-5f);
        scL[t] = sc;
        shL[t] = beta[t] - mu * sc;
    }
    __syncthreads();
    int s = gstart[g], e = gstart[g + 1];
    int c = t & 127, half = t >> 7;
    float sc = scL[c], sh = shL[c];
    float pacc = 0.f;
    for (int n = s + half; n < e; n += 2) {
        size_t i = (size_t)n * NH + c;
        float r = fmaxf(fmaf(z[i], sc, sh), 0.f) + h[i];
        h[i] = r;
        hbf[i] = f2bf(r);
        pacc += r;
    }
    red[t] = pacc;
    __syncthreads();
    if (t < NH) pooled[(size_t)g * NH + t] = red[t] + red[t + NH];
}

// ---------------- pool (layer 0 only) ----------------
__global__ __launch_bounds__(256) void pool_kernel(
    const float* __restrict__ h, const int* __restrict__ gstart,
    float* __restrict__ pooled, int G) {
    int g = blockIdx.x;
    int t = threadIdx.x;
    int s = gstart[g], e = gstart[g + 1];
    int c = t & 127, half = t >> 7;
    float acc = 0.f;
    for (int n = s + half; n < e; n += 2)
        acc += h[(size_t)n * NH + c];
    __shared__ float red[256];
    red[t] = acc;
    __syncthreads();
    if (t < NH) pooled[(size_t)g * NH + t] = red[t] + red[t + NH];
}

// ---------------- JK head ----------------
__global__ void jk_kernel(const float* __restrict__ pooled, const float* __restrict__ jkW,
                          const float* __restrict__ jkb, float* __restrict__ out, int G) {
    int idx = blockIdx.x * blockDim.x + threadIdx.x;
    if (idx >= G * 10) return;
    int g = idx / 10, c = idx % 10;
    float acc = 0.f;
    for (int l = 0; l < LAYERS + 1; ++l) {
        acc += jkb[l * 10 + c];
        const float* pg = pooled + ((size_t)l * G + g) * NH;
        const float* wl = jkW + (size_t)l * NH * 10 + c;
        float s = 0.f;
#pragma unroll 16
        for (int k = 0; k < NH; ++k) s = fmaf(pg[k], wl[k * 10], s);
        acc += s;
    }
    out[idx] = acc;
}

extern "C" void kernel_launch(void* const* d_in, const int* in_sizes, int n_in,
                              void* d_out, int out_size, void* d_ws, size_t ws_size,
                              hipStream_t stream) {
    const float* h_in      = (const float*)d_in[0];
    const float* edge_attr = (const float*)d_in[1];
    const int*   edge_idx  = (const int*)d_in[2];
    const int*   batch     = (const int*)d_in[5];
    const float* emb_W     = (const float*)d_in[6];
    const float* emb_b     = (const float*)d_in[7];
    const float* conv_W    = (const float*)d_in[8];
    const float* conv_b    = (const float*)d_in[9];
    const float* conv_We   = (const float*)d_in[10];
    const float* conv_be   = (const float*)d_in[11];
    const float* bn_gamma  = (const float*)d_in[12];
    const float* bn_beta   = (const float*)d_in[13];
    const float* jk_W      = (const float*)d_in[14];
    const float* jk_b      = (const float*)d_in[15];
    float* out = (float*)d_out;

    const int N = in_sizes[0] / NH;
    const int E = in_sizes[1] / 16;
    const int G = out_size / 10;
    const int NB = (N + 1023) / 1024;

    const int* src = edge_idx;
    const int* dst = edge_idx + E;

    size_t off = 0;
    auto alloc = [&](size_t bytes) -> void* {
        void* p = (char*)d_ws + off;
        off += (bytes + 255) & ~(size_t)255;
        return p;
    };
    float* hbuf = (float*)alloc((size_t)N * NH * 4);
    unsigned short* hbf = (unsigned short*)alloc((size_t)N * NH * 2);
    float* xbuf = (float*)alloc((size_t)N * NH * 4);
    float* zbuf = (float*)alloc((size_t)N * NH * 4);
    float* pooled  = (float*)alloc((size_t)(LAYERS + 1) * G * NH * 4);
    float* easum   = (float*)alloc((size_t)N * 16 * 4);
    size_t zero_off = off;
    float* bnsum   = (float*)alloc((size_t)LAYERS * NH * 4);
    float* bnsumsq = (float*)alloc((size_t)LAYERS * NH * 4);
    int* deg       = (int*)alloc((size_t)N * 4);
    size_t zero_bytes = off - zero_off;
    int* row_start = (int*)alloc((size_t)(N + 1) * 4);
    int* cursor    = (int*)alloc((size_t)N * 4);
    int* gstart    = (int*)alloc((size_t)(G + 1) * 4);
    int* bsum      = (int*)alloc((size_t)NB * 4);
    int2* pk       = (int2*)alloc((size_t)E * 8);
    (void)ws_size; (void)n_in;

    hipMemsetAsync((char*)d_ws + zero_off, 0, zero_bytes, stream);

    hist_gstart_kernel<<<(E + 255) / 256, 256, 0, stream>>>(dst, deg, E, batch, gstart, N, G);
    block_sum_kernel<<<NB, 256, 0, stream>>>(deg, bsum, N);
    scan_partials_kernel<<<1, 1024, 0, stream>>>(bsum, NB, row_start, N);
    local_scan_kernel<<<NB, 256, 0, stream>>>(deg, bsum, row_start, cursor, N);
    scatter_kernel<<<(E + 255) / 256, 256, 0, stream>>>(src, dst, cursor, pk, E);
    easum_kernel<<<(N + 15) / 16, 256, 0, stream>>>(edge_attr, pk, row_start, easum, N);

    dim3 gemm_grid((N + 127) / 128);
    dim3 agg_grid((N + 3) / 4);

    // embedding: writes h (fp32) and hbf (bf16 mirror)
    gemm128_kernel<<<gemm_grid, 256, 0, stream>>>(h_in, emb_W, emb_b, hbuf, N,
                                                  nullptr, nullptr, hbf);
    pool_kernel<<<G, 256, 0, stream>>>(hbuf, gstart, pooled, G);

    for (int l = 0; l < LAYERS; ++l) {
        aggregate_kernel<<<agg_grid, 256, 0, stream>>>(
            hbuf, (const unsigned*)hbf, pk, row_start, easum,
            conv_We + (size_t)l * 16 * NH, conv_be + (size_t)l * NH, xbuf, N);
        gemm128_kernel<<<gemm_grid, 256, 0, stream>>>(
            xbuf, conv_W + (size_t)l * NH * NH, conv_b + (size_t)l * NH, zbuf, N,
            bnsum + (size_t)l * NH, bnsumsq + (size_t)l * NH, nullptr);
        update_pool_kernel<<<G, 256, 0, stream>>>(
            zbuf, hbuf, hbf, bnsum + (size_t)l * NH, bnsumsq + (size_t)l * NH,
            bn_gamma + (size_t)l * NH, bn_beta + (size_t)l * NH,
            1.0f / (float)N, gstart, pooled + (size_t)(l + 1) * G * NH);
    }

    jk_kernel<<<(G * 10 + 255) / 256, 256, 0, stream>>>(pooled, jk_W, jk_b, out, G);
}